// Round 1
// 226.673 us; speedup vs baseline: 1.1425x; 1.1425x over previous
//
#include <hip/hip_runtime.h>

#define N_NODES_C 50000
#define N_EDGES_C 800000
#define IN_FEATS_C 128
#define HEADS_C 8
#define HD_C 256            // HEADS * OUT_FEATS
#define NEG_SLOPE_C 0.2f
#define SCAN_NBLK 49        // ceil(50000/1024)
#define LDT 136             // LDS row stride in shorts (272 B = 17*16, 16B-aligned)

#define GEMM_BLOCKS 782     // ceil(50000/128) * 2 channel tiles
#define DEG_BLOCKS 242
#define K1_GRID (GEMM_BLOCKS + DEG_BLOCKS)   // 1024

typedef __attribute__((ext_vector_type(8))) short bf16x8;
typedef __attribute__((ext_vector_type(4))) float floatx4;

__device__ inline unsigned short f2bf(float f) {
  unsigned int u = __float_as_uint(f);
  unsigned int r = (u + 0x7FFFu + ((u >> 16) & 1u)) >> 16;   // RNE
  return (unsigned short)r;
}
__device__ inline float bf2f(unsigned short s) {
  unsigned int u = ((unsigned int)s) << 16;
  return __uint_as_float(u);
}

// 49-entry exclusive scan of bsum into sboff[64] (first wave only, then barrier)
__device__ inline void boff_scan(const int* __restrict__ bsum, int* sboff) {
  int t = threadIdx.x;
  if (t < 64) {
    int own = (t < SCAN_NBLK) ? bsum[t] : 0;
    int v = own;
#pragma unroll
    for (int off = 1; off < 64; off <<= 1) {
      int u = __shfl_up(v, off);
      if (t >= off) v += u;
    }
    sboff[t] = v - own;   // exclusive
  }
  __syncthreads();
}

// ============ K1: MFMA gemm + fused el/er (0..781) || deg+rank (782..1023) ============
// gemm block: 128 nodes x 128 channels (= 4 complete heads), K=128.
// el/er computed in-epilogue from the repacked bf16 tile in LDS (no elr pass).
// deg path also records each edge's arrival rank, so scatter needs no atomics.
__global__ __launch_bounds__(256) void front_kernel(
    const float* __restrict__ feat, const float* __restrict__ W,
    const float* __restrict__ attn_l, const float* __restrict__ attn_r,
    const int* __restrict__ dst,
    unsigned short* __restrict__ feat_hd_bf,
    float* __restrict__ el, float* __restrict__ er,
    int* __restrict__ deg, int* __restrict__ rank) {
  __shared__ __align__(16) unsigned short sA[128 * LDT];   // 34816 B; reused as sOut
  __shared__ float sAttnL[128];
  __shared__ float sAttnR[128];
  const int bid = blockIdx.x;
  const int t = threadIdx.x;

  if (bid >= GEMM_BLOCKS) {
    // ---- degree histogram + rank capture ----
    for (int e = (bid - GEMM_BLOCKS) * 256 + t; e < N_EDGES_C;
         e += DEG_BLOCKS * 256)
      rank[e] = atomicAdd(&deg[dst[e]], 1);
    return;
  }

  const int nt = bid & 1;              // channel tile (heads nt*4 .. nt*4+3)
  const int mt = bid >> 1;
  const int m0 = mt * 128;
  const int n0 = nt * 128;

  // stage attn slices for this tile's 128 channels
  if (t < 128) {
    sAttnL[t] = attn_l[n0 + t];
    sAttnR[t] = attn_r[n0 + t];
  }
  // stage A: 128 rows x 32 float4 of feat -> bf16
#pragma unroll
  for (int i = 0; i < 16; ++i) {
    int idx = t + i * 256;
    int row = idx >> 5;
    int c4 = idx & 31;
    int gn = m0 + row;
    float4 v = (gn < N_NODES_C)
                   ? *(const float4*)&feat[(size_t)gn * IN_FEATS_C + c4 * 4]
                   : make_float4(0.f, 0.f, 0.f, 0.f);
    ushort4 b;
    b.x = f2bf(v.x); b.y = f2bf(v.y); b.z = f2bf(v.z); b.w = f2bf(v.w);
    *(ushort4*)&sA[row * LDT + c4 * 4] = b;
  }
  __syncthreads();

  const int wid = t >> 6;
  const int lane = t & 63;
  const int quad = lane >> 4;
  const int l16 = lane & 15;
  const int wm = (wid & 1) * 64;
  const int wn = (wid >> 1) * 64;

  floatx4 acc[4][4];
#pragma unroll
  for (int i = 0; i < 4; ++i)
#pragma unroll
    for (int j = 0; j < 4; ++j) acc[i][j] = (floatx4){0.f, 0.f, 0.f, 0.f};

#pragma unroll
  for (int ks = 0; ks < 4; ++ks) {
    int k0 = ks * 32 + quad * 8;
    bf16x8 bfv[4];
#pragma unroll
    for (int n2 = 0; n2 < 4; ++n2) {
      const float* wp = &W[(size_t)(n0 + wn + n2 * 16 + l16) * IN_FEATS_C + k0];
      float4 w0 = *(const float4*)wp;
      float4 w1 = *(const float4*)(wp + 4);
      bf16x8 b;
      b[0] = (short)f2bf(w0.x); b[1] = (short)f2bf(w0.y);
      b[2] = (short)f2bf(w0.z); b[3] = (short)f2bf(w0.w);
      b[4] = (short)f2bf(w1.x); b[5] = (short)f2bf(w1.y);
      b[6] = (short)f2bf(w1.z); b[7] = (short)f2bf(w1.w);
      bfv[n2] = b;
    }
    bf16x8 af[4];
#pragma unroll
    for (int m2 = 0; m2 < 4; ++m2)
      af[m2] = *(const bf16x8*)&sA[(wm + m2 * 16 + l16) * LDT + k0];
#pragma unroll
    for (int m2 = 0; m2 < 4; ++m2)
#pragma unroll
      for (int n2 = 0; n2 < 4; ++n2)
        acc[m2][n2] = __builtin_amdgcn_mfma_f32_16x16x32_bf16(
            af[m2], bfv[n2], acc[m2][n2], 0, 0, 0);
  }
  __syncthreads();

  // epilogue: D layout col=l16, row=quad*4+reg -> repack via LDS
#pragma unroll
  for (int m2 = 0; m2 < 4; ++m2)
#pragma unroll
    for (int n2 = 0; n2 < 4; ++n2)
#pragma unroll
      for (int r = 0; r < 4; ++r) {
        int row = wm + m2 * 16 + quad * 4 + r;
        int col = wn + n2 * 16 + l16;
        sA[row * LDT + col] = f2bf(acc[m2][n2][r]);
      }
  __syncthreads();

  // coalesced store of the bf16 tile
#pragma unroll
  for (int i = 0; i < 8; ++i) {
    int idx = t + i * 256;
    int row = idx >> 4;
    int ch = idx & 15;
    int gn = m0 + row;
    if (gn < N_NODES_C) {
      *(uint4*)&feat_hd_bf[(size_t)gn * HD_C + n0 + ch * 8] =
          *(const uint4*)&sA[row * LDT + ch * 8];
    }
  }

  // fused el/er: thread t -> row t>>1, head-pair t&1 (2 heads x 32 ch)
  {
    int row = t >> 1;
    int hh = t & 1;
    int gn = m0 + row;
    if (gn < N_NODES_C) {
      const unsigned short* pr = &sA[row * LDT + hh * 64];
      const float* al = &sAttnL[hh * 64];
      const float* ar = &sAttnR[hh * 64];
      float el0 = 0.f, el1 = 0.f, er0 = 0.f, er1 = 0.f;
#pragma unroll
      for (int d = 0; d < 32; ++d) {
        float v0 = bf2f(pr[d]);
        float v1 = bf2f(pr[32 + d]);
        el0 = fmaf(v0, al[d], el0);
        er0 = fmaf(v0, ar[d], er0);
        el1 = fmaf(v1, al[32 + d], el1);
        er1 = fmaf(v1, ar[32 + d], er1);
      }
      int gh = nt * 4 + hh * 2;
      el[gn * HEADS_C + gh + 0] = el0;
      el[gn * HEADS_C + gh + 1] = el1;
      er[gn * HEADS_C + gh + 0] = er0;
      er[gn * HEADS_C + gh + 1] = er1;
    }
  }
}

// ============ scan1: 256 threads x 4 elements, block-wise inclusive scan ============
__global__ __launch_bounds__(256) void scan1_kernel(
    const int* __restrict__ deg, int* __restrict__ row_start,
    int* __restrict__ bsum) {
  __shared__ int s[256];
  int b = blockIdx.x, t = threadIdx.x;
  int i0 = b * 1024 + t * 4;
  int d0 = 0, d1 = 0, d2 = 0, d3 = 0;
  if (i0 + 4 <= N_NODES_C) {
    int4 d = *(const int4*)&deg[i0];
    d0 = d.x; d1 = d.y; d2 = d.z; d3 = d.w;
  } else {
    if (i0 + 0 < N_NODES_C) d0 = deg[i0 + 0];
    if (i0 + 1 < N_NODES_C) d1 = deg[i0 + 1];
    if (i0 + 2 < N_NODES_C) d2 = deg[i0 + 2];
    if (i0 + 3 < N_NODES_C) d3 = deg[i0 + 3];
  }
  int l1 = d0, l2 = l1 + d1, l3 = l2 + d2, l4 = l3 + d3;
  s[t] = l4;
  __syncthreads();
#pragma unroll
  for (int off = 1; off < 256; off <<= 1) {
    int add = (t >= off) ? s[t - off] : 0;
    __syncthreads();
    s[t] += add;
    __syncthreads();
  }
  int excl = s[t] - l4;
  if (i0 + 0 < N_NODES_C) row_start[i0 + 0] = excl + l1;   // inclusive
  if (i0 + 1 < N_NODES_C) row_start[i0 + 1] = excl + l2;
  if (i0 + 2 < N_NODES_C) row_start[i0 + 2] = excl + l3;
  if (i0 + 3 < N_NODES_C) row_start[i0 + 3] = excl + l4;
  if (t == 255) bsum[b] = s[255];
}

// ============ scatter: atomic-free, absolute CSR position from captured rank ============
__global__ __launch_bounds__(256) void scatter_kernel(
    const int* __restrict__ src, const int* __restrict__ dst,
    const int* __restrict__ row_start, const int* __restrict__ deg,
    const int* __restrict__ bsum, const int* __restrict__ rank,
    int* __restrict__ csr_src) {
  __shared__ int sboff[64];
  boff_scan(bsum, sboff);
  int e = blockIdx.x * 256 + threadIdx.x;
  if (e >= N_EDGES_C) return;
  int d = dst[e];
  int pos = row_start[d] - deg[d] + sboff[d >> 10] + rank[e];
  csr_src[pos] = src[e];
}

// ============ aggregation over CSR: wave per dst node ============
// 8-edge blocks with: one per-lane index load + shfl broadcast, next-block
// index prefetch overlapped with FMA, and a masked final block so the
// remainder gets the same 8-deep gather ILP as the main loop.
__global__ __launch_bounds__(256) void agg_csr_kernel(
    const unsigned short* __restrict__ feat_hd_bf, const float* __restrict__ el,
    const float* __restrict__ er, const int* __restrict__ row_start,
    const int* __restrict__ deg, const int* __restrict__ bsum,
    const int* __restrict__ csr_src, float* __restrict__ out) {
  __shared__ int sboff[64];
  boff_scan(bsum, sboff);
  int gid = blockIdx.x * 256 + threadIdx.x;
  int node = gid >> 6;
  int lane = threadIdx.x & 63;
  if (node >= N_NODES_C) return;
  int h = lane >> 3;
  int j8 = lane & 7;
  int hbase = lane & 56;               // h*8
  int c = lane * 4;
  float er_d = er[node * HEADS_C + h];
  int dg = deg[node];
  int rs = row_start[node] - dg + sboff[node >> 10];
  float4 acc = make_float4(0.f, 0.f, 0.f, 0.f);
  float zsum = 0.f;

  int nb = (dg + 7) >> 3;              // number of 8-edge blocks (last one masked)
  if (nb > 0) {
    int myidx = csr_src[rs + min(j8, dg - 1)];
    for (int b = 0; b < nb; ++b) {
      int e0 = b * 8;
      // gather the 8 feat rows for this block (indices broadcast via shfl)
      ushort4 f[8];
#pragma unroll
      for (int j = 0; j < 8; ++j) {
        int sj = __shfl(myidx, j);
        f[j] = *(const ushort4*)&feat_hd_bf[(size_t)sj * HD_C + c];
      }
      // this lane's edge weight (masked to 0 past the segment end)
      float x = el[myidx * HEADS_C + h] + er_d;
      x = x > 0.f ? x : NEG_SLOPE_C * x;
      float wv = (e0 + j8 < dg) ? __expf(x) : 0.f;
      // prefetch next block's index (clamped -> always in-segment, branchless)
      int nidx = csr_src[rs + min(e0 + 8 + j8, dg - 1)];
      // broadcast per-head weights for the 8 edges
      float wj[8];
#pragma unroll
      for (int j = 0; j < 8; ++j) wj[j] = __shfl(wv, hbase + j);
      zsum += ((wj[0] + wj[1]) + (wj[2] + wj[3])) +
              ((wj[4] + wj[5]) + (wj[6] + wj[7]));
#pragma unroll
      for (int j = 0; j < 8; ++j) {
        acc.x = fmaf(wj[j], bf2f(f[j].x), acc.x);
        acc.y = fmaf(wj[j], bf2f(f[j].y), acc.y);
        acc.z = fmaf(wj[j], bf2f(f[j].z), acc.z);
        acc.w = fmaf(wj[j], bf2f(f[j].w), acc.w);
      }
      myidx = nidx;
    }
  }

  float inv = (dg > 0) ? 1.f / zsum : 0.f;
  acc.x *= inv; acc.y *= inv; acc.z *= inv; acc.w *= inv;
  *(float4*)&out[(size_t)node * HD_C + c] = acc;
}

extern "C" void kernel_launch(void* const* d_in, const int* in_sizes, int n_in,
                              void* d_out, int out_size, void* d_ws, size_t ws_size,
                              hipStream_t stream) {
  const float* feat   = (const float*)d_in[0];
  const float* W      = (const float*)d_in[1];
  const float* attn_l = (const float*)d_in[2];
  const float* attn_r = (const float*)d_in[3];
  const int* src      = (const int*)d_in[4];
  const int* dst      = (const int*)d_in[5];
  float* out = (float*)d_out;

  char* ws = (char*)d_ws;
  unsigned short* feat_hd_bf = (unsigned short*)ws;  ws += (size_t)N_NODES_C * HD_C * 2;     // 25.6 MB
  float* el      = (float*)ws;                       ws += (size_t)N_NODES_C * HEADS_C * 4;  // 1.6 MB
  float* er      = (float*)ws;                       ws += (size_t)N_NODES_C * HEADS_C * 4;  // 1.6 MB
  int* deg       = (int*)ws;                         ws += (size_t)N_NODES_C * 4;
  int* row_start = (int*)ws;                         ws += (size_t)N_NODES_C * 4;
  int* bsum      = (int*)ws;                         ws += 64 * 4;
  int* csr_src   = (int*)ws;                         ws += (size_t)N_EDGES_C * 4;            // 3.2 MB
  int* rank      = (int*)ws;                         ws += (size_t)N_EDGES_C * 4;            // 3.2 MB

  hipMemsetAsync(deg, 0, (size_t)N_NODES_C * 4, stream);   // deg only (no cursor)

  front_kernel<<<K1_GRID, 256, 0, stream>>>(feat, W, attn_l, attn_r, dst,
                                            feat_hd_bf, el, er, deg, rank);

  scan1_kernel<<<SCAN_NBLK, 256, 0, stream>>>(deg, row_start, bsum);

  scatter_kernel<<<(N_EDGES_C + 255) / 256, 256, 0, stream>>>(
      src, dst, row_start, deg, bsum, rank, csr_src);

  agg_csr_kernel<<<(N_NODES_C + 3) / 4, 256, 0, stream>>>(
      feat_hd_bf, el, er, row_start, deg, bsum, csr_src, out);
}